// Round 12
// baseline (92.020 us; speedup 1.0000x reference)
//
#include <hip/hip_runtime.h>

using f32x4  = __attribute__((ext_vector_type(4))) float;
using u16x8  = __attribute__((ext_vector_type(8))) unsigned short;
using u16x4  = __attribute__((ext_vector_type(4))) unsigned short;
using bf16x8 = __attribute__((ext_vector_type(8))) __bf16;

__device__ __forceinline__ unsigned short f2bf(float f){
  unsigned int u = __builtin_bit_cast(unsigned int, f);
  u += 0x7fffu + ((u >> 16) & 1u);          // RNE to bf16
  return (unsigned short)(u >> 16);
}
__device__ __forceinline__ float bf2f(unsigned short h){
  return __builtin_bit_cast(float, ((unsigned int)h) << 16);
}
__device__ __forceinline__ unsigned short f2h(float f){
  return __builtin_bit_cast(unsigned short, (_Float16)f);
}
__device__ __forceinline__ float h2f(unsigned short h){
  return (float)__builtin_bit_cast(_Float16, h);
}
__device__ __forceinline__ f32x4 mfma_bf16(u16x8 a, u16x8 b, f32x4 c){
  return __builtin_amdgcn_mfma_f32_16x16x32_bf16(
      __builtin_bit_cast(bf16x8, a), __builtin_bit_cast(bf16x8, b), c, 0, 0, 0);
}
__device__ __forceinline__ float fast_sigmoid(float x){
  return __builtin_amdgcn_rcpf(1.0f + __builtin_amdgcn_exp2f(-1.44269504f * x));
}

constexpr int C_  = 256;
constexpr int L_  = 64;
constexpr int CHW = C_ * 64;   // 16384

// LDS operand layout (bf16/fp16, 256 c x 16 p): el(c,p) = ((c>>3)*16 + p)*8 + (c&7)
// B-fragment (kc, lane): b128 at kc*512 + (lane>>4)*128 + (lane&15)*8
// staging: b128 at (ss*16+sp)*8 ; epilogue rows ro..ro+3: b64 at
// ((ro>>3)*16 + m)*8 + (ro&7)

// Raw barrier: LDS ops drained, global prefetch loads stay in flight
#define BAR_LDS() do {                                        \
    asm volatile("s_waitcnt lgkmcnt(0)" ::: "memory");        \
    __builtin_amdgcn_s_barrier();                             \
    asm volatile("" ::: "memory");                            \
  } while (0)

// Phase-skewed schedule, constant per-role work (R11) + chain shortening (R12):
//   P: sf+zi+k reads FIRST -> 8x depth-4 MFMA chains -> blend/write s_l ->
//      staging commit+issue (tail)
//   G: staging commit+issue (head) -> zf reads -> 8x depth-4 MFMA chains ->
//      sigmoid -> k write
// G's depth-8 accumulator chain was the straggler (~520 cy of dependent-MFMA
// latency); split to glA/glB depth-4 like P. P's zi/k reads hoisted before
// MFMA so their latency hides under the accumulate phase.

__global__ __launch_bounds__(512, 2)
void kalman_kernel(const float* __restrict__ z,  const float* __restrict__ Wg,
                   const float* __restrict__ bg, const float* __restrict__ Wp,
                   const float* __restrict__ bp, float* __restrict__ out)
{
  __shared__ unsigned short zbuf[4][4096];   // z ring (2-step prefetch depth)
  __shared__ unsigned short sbuf[2][4096];   // state ping-pong (bf16)
  __shared__ unsigned short kbuf[2][4096];   // gain k ping-pong (fp16)

  // XCD swizzle: siblings (same b, q=0..3) share an XCD's L2
  const int lx  = (int)blockIdx.x;
  const int xcd = lx & 7;
  const int loc = lx >> 3;
  const int b   = xcd + 8 * (loc >> 2);
  const int q   = loc & 3;

  const int t    = (int)threadIdx.x;
  const int lane = t & 63;
  const int wv   = t >> 6;
  const int role = wv >> 2;           // 0 = P (predict+blend), 1 = G (gain, 1 step ahead)
  const int rw   = wv & 3;            // owns M-tiles rw*4 .. rw*4+3
  const int m    = lane & 15;
  const int g    = lane >> 4;

  const float* zg = z + (size_t)b * L_ * CHW + q * 16;

  // ---- weights for THIS role only: 4 M-tiles x 8 K-chunks (scalar RNE cvt) ----
  const float* Wsel = (role == 0) ? Wp : Wg;
  const float* bsrc = (role == 0) ? bp : bg;
  u16x8 wf[4][8];
  f32x4 bsel[4];
  #pragma unroll
  for (int mi = 0; mi < 4; ++mi){
    const int mt = rw * 4 + mi;
    const float* src = Wsel + (size_t)(mt * 16 + m) * 256 + g * 8;
    #pragma unroll
    for (int kc = 0; kc < 8; ++kc){
      f32x4 a0 = *(const f32x4*)(src + kc * 32);
      f32x4 a1 = *(const f32x4*)(src + kc * 32 + 4);
      #pragma unroll
      for (int j = 0; j < 4; ++j){
        wf[mi][kc][j]     = f2bf(a0[j]);
        wf[mi][kc][j + 4] = f2bf(a1[j]);
      }
    }
    bsel[mi] = *(const f32x4*)(bsrc + mt * 16 + g * 4);
  }

  // staging ids: thread t stages rows ss*8..+7 at pixel sp
  const int sp = t & 15;
  const int ss = t >> 4;
  const float* st_src = zg + ss * 8 * 64 + sp;
  const int st_dst = (ss * 16 + sp) * 8;
  const int boff   = g * 128 + m * 8;

  // ---- prologue: z0 -> sbuf[0], z1 -> zbuf[1], z2 -> zbuf[2]; issue z3 ----
  {
    float v0[8], v1[8], v2[8];
    #pragma unroll
    for (int j = 0; j < 8; ++j) v0[j] = st_src[j * 64];
    #pragma unroll
    for (int j = 0; j < 8; ++j) v1[j] = st_src[CHW + j * 64];
    #pragma unroll
    for (int j = 0; j < 8; ++j) v2[j] = st_src[2 * CHW + j * 64];
    u16x8 u0, u1, u2;
    #pragma unroll
    for (int j = 0; j < 8; ++j){ u0[j] = f2bf(v0[j]); u1[j] = f2bf(v1[j]); u2[j] = f2bf(v2[j]); }
    *(u16x8*)(&sbuf[0][st_dst]) = u0;
    *(u16x8*)(&zbuf[1][st_dst]) = u1;
    *(u16x8*)(&zbuf[2][st_dst]) = u2;
  }
  float pf[8];
  const float* pfp = st_src + 3 * (size_t)CHW;   // z3
  #pragma unroll
  for (int j = 0; j < 8; ++j) pf[j] = pfp[j * 64];
  pfp += CHW;                                    // next issue: z4
  __syncthreads();

  // k_1 from z_1 (G-waves only)
  if (role == 1){
    u16x8 zf[8];
    #pragma unroll
    for (int kc = 0; kc < 8; ++kc) zf[kc] = *(const u16x8*)(&zbuf[1][kc * 512 + boff]);
    f32x4 glA[4] = {bsel[0], bsel[1], bsel[2], bsel[3]};
    f32x4 glB[4] = {{0,0,0,0},{0,0,0,0},{0,0,0,0},{0,0,0,0}};
    #pragma unroll
    for (int kc = 0; kc < 4; ++kc)
      #pragma unroll
      for (int mi = 0; mi < 4; ++mi){
        glA[mi] = mfma_bf16(wf[mi][kc],     zf[kc],     glA[mi]);
        glB[mi] = mfma_bf16(wf[mi][kc + 4], zf[kc + 4], glB[mi]);
      }
    #pragma unroll
    for (int mi = 0; mi < 4; ++mi){
      const int ro = (rw * 4 + mi) * 16 + g * 4;
      const int el = ((ro >> 3) * 16 + m) * 8 + (ro & 7);
      u16x4 kk;
      #pragma unroll
      for (int r = 0; r < 4; ++r) kk[r] = f2h(fast_sigmoid(glA[mi][r] + glB[mi][r]));
      *(u16x4*)(&kbuf[1][el]) = kk;
    }
  }
  __syncthreads();

  for (int l = 1; l < 63; ++l){
    if (role == 0){
      // ================= P: critical chain first, staging at tail =================
      const unsigned short* sb  = sbuf[(l - 1) & 1];
      const unsigned short* zbl = zbuf[l & 3];
      const unsigned short* kb  = kbuf[l & 1];
      unsigned short* sbw = sbuf[l & 1];

      // ALL reads first: sf (chain head) + zi/k (latency hidden under MFMA)
      u16x8 sf[8];
      #pragma unroll
      for (int kc = 0; kc < 8; ++kc) sf[kc] = *(const u16x8*)(sb + kc * 512 + boff);
      u16x4 zi4[4], k4[4];
      #pragma unroll
      for (int mi = 0; mi < 4; ++mi){
        const int ro = (rw * 4 + mi) * 16 + g * 4;
        const int el = ((ro >> 3) * 16 + m) * 8 + (ro & 7);
        zi4[mi] = *(const u16x4*)(zbl + el);
        k4[mi]  = *(const u16x4*)(kb + el);
      }

      f32x4 zpA[4] = {bsel[0], bsel[1], bsel[2], bsel[3]};
      f32x4 zpB[4] = {{0,0,0,0},{0,0,0,0},{0,0,0,0},{0,0,0,0}};
      __builtin_amdgcn_s_setprio(1);
      #pragma unroll
      for (int kc = 0; kc < 4; ++kc)
        #pragma unroll
        for (int mi = 0; mi < 4; ++mi){
          zpA[mi] = mfma_bf16(wf[mi][kc],     sf[kc],     zpA[mi]);
          zpB[mi] = mfma_bf16(wf[mi][kc + 4], sf[kc + 4], zpB[mi]);
        }
      __builtin_amdgcn_s_setprio(0);

      #pragma unroll
      for (int mi = 0; mi < 4; ++mi){
        const int ro = (rw * 4 + mi) * 16 + g * 4;
        const int el = ((ro >> 3) * 16 + m) * 8 + (ro & 7);
        u16x4 sh;
        #pragma unroll
        for (int r = 0; r < 4; ++r){
          float zpr = zpA[mi][r] + zpB[mi][r];
          float zh  = zpr + h2f(k4[mi][r]) * (bf2f(zi4[mi][r]) - zpr);
          sh[r] = f2bf(zh);
        }
        *(u16x4*)(sbw + el) = sh;
      }

      // staging at TAIL: commit z_{l+2}, issue z_{l+3}
      if (l <= 61){
        u16x8 u;
        #pragma unroll
        for (int j = 0; j < 8; ++j) u[j] = f2bf(pf[j]);
        *(u16x8*)(&zbuf[(l + 2) & 3][st_dst]) = u;
      }
      if (l <= 60){
        #pragma unroll
        for (int j = 0; j < 8; ++j) pf[j] = pfp[j * 64];
        pfp += CHW;
      }
    } else {
      // ================= G: staging at head, then gain for l+1 =================
      if (l <= 61){
        u16x8 u;
        #pragma unroll
        for (int j = 0; j < 8; ++j) u[j] = f2bf(pf[j]);
        *(u16x8*)(&zbuf[(l + 2) & 3][st_dst]) = u;
      }
      if (l <= 60){
        #pragma unroll
        for (int j = 0; j < 8; ++j) pf[j] = pfp[j * 64];
        pfp += CHW;
      }

      const unsigned short* zb = zbuf[(l + 1) & 3];
      unsigned short* kw = kbuf[(l + 1) & 1];

      u16x8 zf[8];
      #pragma unroll
      for (int kc = 0; kc < 8; ++kc) zf[kc] = *(const u16x8*)(zb + kc * 512 + boff);

      // split chains: depth 4 each, 8 independent accumulators
      f32x4 glA[4] = {bsel[0], bsel[1], bsel[2], bsel[3]};
      f32x4 glB[4] = {{0,0,0,0},{0,0,0,0},{0,0,0,0},{0,0,0,0}};
      #pragma unroll
      for (int kc = 0; kc < 4; ++kc)
        #pragma unroll
        for (int mi = 0; mi < 4; ++mi){
          glA[mi] = mfma_bf16(wf[mi][kc],     zf[kc],     glA[mi]);
          glB[mi] = mfma_bf16(wf[mi][kc + 4], zf[kc + 4], glB[mi]);
        }

      #pragma unroll
      for (int mi = 0; mi < 4; ++mi){
        const int ro = (rw * 4 + mi) * 16 + g * 4;
        const int el = ((ro >> 3) * 16 + m) * 8 + (ro & 7);
        u16x4 kk;
        #pragma unroll
        for (int r = 0; r < 4; ++r) kk[r] = f2h(fast_sigmoid(glA[mi][r] + glB[mi][r]));
        *(u16x4*)(kw + el) = kk;
      }
    }

    BAR_LDS();
  }

  // ---- peeled final step l = 63 (P only): out (f32) from regs ----
  if (role == 0){
    const unsigned short* sb  = sbuf[0];          // s_62  ((63-1)&1)
    const unsigned short* zbl = zbuf[3];          // z_63  (63&3)
    const unsigned short* kb  = kbuf[1];          // k_63  (63&1)

    u16x8 sf[8];
    #pragma unroll
    for (int kc = 0; kc < 8; ++kc) sf[kc] = *(const u16x8*)(sb + kc * 512 + boff);
    u16x4 zi4[4], k4[4];
    #pragma unroll
    for (int mi = 0; mi < 4; ++mi){
      const int ro = (rw * 4 + mi) * 16 + g * 4;
      const int el = ((ro >> 3) * 16 + m) * 8 + (ro & 7);
      zi4[mi] = *(const u16x4*)(zbl + el);
      k4[mi]  = *(const u16x4*)(kb + el);
    }

    f32x4 zpA[4] = {bsel[0], bsel[1], bsel[2], bsel[3]};
    f32x4 zpB[4] = {{0,0,0,0},{0,0,0,0},{0,0,0,0},{0,0,0,0}};
    #pragma unroll
    for (int kc = 0; kc < 4; ++kc)
      #pragma unroll
      for (int mi = 0; mi < 4; ++mi){
        zpA[mi] = mfma_bf16(wf[mi][kc],     sf[kc],     zpA[mi]);
        zpB[mi] = mfma_bf16(wf[mi][kc + 4], sf[kc + 4], zpB[mi]);
      }

    #pragma unroll
    for (int mi = 0; mi < 4; ++mi){
      const int ro = (rw * 4 + mi) * 16 + g * 4;
      float* o = out + ((size_t)b * 256 + ro) * 64 + q * 16 + m;
      #pragma unroll
      for (int r = 0; r < 4; ++r){
        float zpr = zpA[mi][r] + zpB[mi][r];
        o[r * 64] = zpr + h2f(k4[mi][r]) * (bf2f(zi4[mi][r]) - zpr);
      }
    }
  }
}

extern "C" void kernel_launch(void* const* d_in, const int* in_sizes, int n_in,
                              void* d_out, int out_size, void* d_ws, size_t ws_size,
                              hipStream_t stream)
{
  const float* z  = (const float*)d_in[0];
  const float* Wg = (const float*)d_in[1];
  const float* bg = (const float*)d_in[2];
  const float* Wp = (const float*)d_in[3];
  const float* bp = (const float*)d_in[4];
  float* out = (float*)d_out;
  hipLaunchKernelGGL(kalman_kernel, dim3(256), dim3(512), 0, stream,
                     z, Wg, bg, Wp, bp, out);
}

// Round 13
// 90.510 us; speedup vs baseline: 1.0167x; 1.0167x over previous
//
#include <hip/hip_runtime.h>

using f32x4  = __attribute__((ext_vector_type(4))) float;
using u16x8  = __attribute__((ext_vector_type(8))) unsigned short;
using u16x4  = __attribute__((ext_vector_type(4))) unsigned short;
using bf16x8 = __attribute__((ext_vector_type(8))) __bf16;

__device__ __forceinline__ unsigned short f2bf(float f){
  unsigned int u = __builtin_bit_cast(unsigned int, f);
  u += 0x7fffu + ((u >> 16) & 1u);          // RNE to bf16
  return (unsigned short)(u >> 16);
}
__device__ __forceinline__ float bf2f(unsigned short h){
  return __builtin_bit_cast(float, ((unsigned int)h) << 16);
}
__device__ __forceinline__ unsigned short f2h(float f){
  return __builtin_bit_cast(unsigned short, (_Float16)f);
}
__device__ __forceinline__ float h2f(unsigned short h){
  return (float)__builtin_bit_cast(_Float16, h);
}
__device__ __forceinline__ f32x4 mfma_bf16(u16x8 a, u16x8 b, f32x4 c){
  return __builtin_amdgcn_mfma_f32_16x16x32_bf16(
      __builtin_bit_cast(bf16x8, a), __builtin_bit_cast(bf16x8, b), c, 0, 0, 0);
}
__device__ __forceinline__ float fast_sigmoid(float x){
  return __builtin_amdgcn_rcpf(1.0f + __builtin_amdgcn_exp2f(-1.44269504f * x));
}

constexpr int C_  = 256;
constexpr int L_  = 64;
constexpr int CHW = C_ * 64;   // 16384

// LDS operand layout (bf16/fp16, 256 c x 16 p): el(c,p) = ((c>>3)*16 + p)*8 + (c&7)
// B-fragment (kc, lane): b128 at kc*512 + (lane>>4)*128 + (lane&15)*8
// staging (1024 thr): thread t = (cq, px) stages chans cq*4..+3 at pixel px:
//   b64 at ((cq>>1)*16 + px)*8 + (cq&1)*4
// epilogue rows ro..ro+3: b64 at ((ro>>3)*16 + m)*8 + (ro&7)

// Raw barrier: LDS ops drained, global prefetch loads stay in flight
#define BAR_LDS() do {                                        \
    asm volatile("s_waitcnt lgkmcnt(0)" ::: "memory");        \
    __builtin_amdgcn_s_barrier();                             \
    asm volatile("" ::: "memory");                            \
  } while (0)

// R13: 16 waves (4/SIMD) for latency hiding; 2 M-tiles/wave; R11 phase skew
// kept (P: compute head / staging tail; G: staging head / compute tail).

__global__ __launch_bounds__(1024, 4)
void kalman_kernel(const float* __restrict__ z,  const float* __restrict__ Wg,
                   const float* __restrict__ bg, const float* __restrict__ Wp,
                   const float* __restrict__ bp, float* __restrict__ out)
{
  __shared__ unsigned short zbuf[4][4096];   // z ring (2-step prefetch depth)
  __shared__ unsigned short sbuf[2][4096];   // state ping-pong (bf16)
  __shared__ unsigned short kbuf[2][4096];   // gain k ping-pong (fp16)

  // XCD swizzle: siblings (same b, q=0..3) share an XCD's L2
  const int lx  = (int)blockIdx.x;
  const int xcd = lx & 7;
  const int loc = lx >> 3;
  const int b   = xcd + 8 * (loc >> 2);
  const int q   = loc & 3;

  const int t    = (int)threadIdx.x;
  const int lane = t & 63;
  const int wv   = t >> 6;            // 0..15
  const int role = wv >> 3;           // 0 = P (waves 0-7), 1 = G (waves 8-15)
  const int rw   = wv & 7;            // owns M-tiles rw*2, rw*2+1
  const int m    = lane & 15;
  const int g    = lane >> 4;

  const float* zg = z + (size_t)b * L_ * CHW + q * 16;

  // ---- per-role weights: 2 M-tiles x 8 K-chunks (64 VGPR) ----
  const float* Wsel = (role == 0) ? Wp : Wg;
  const float* bsrc = (role == 0) ? bp : bg;
  u16x8 wf[2][8];
  f32x4 bsel[2];
  #pragma unroll
  for (int mi = 0; mi < 2; ++mi){
    const int mt = rw * 2 + mi;
    const float* src = Wsel + (size_t)(mt * 16 + m) * 256 + g * 8;
    #pragma unroll
    for (int kc = 0; kc < 8; ++kc){
      f32x4 a0 = *(const f32x4*)(src + kc * 32);
      f32x4 a1 = *(const f32x4*)(src + kc * 32 + 4);
      #pragma unroll
      for (int j = 0; j < 4; ++j){
        wf[mi][kc][j]     = f2bf(a0[j]);
        wf[mi][kc][j + 4] = f2bf(a1[j]);
      }
    }
    bsel[mi] = *(const f32x4*)(bsrc + mt * 16 + g * 4);
  }

  // staging ids: thread t stages chans cq*4..+3 at pixel px (4 els, b64)
  const int px = t & 15;
  const int cq = t >> 4;              // 0..63
  const float* st_src = zg + cq * 4 * 64 + px;   // + l*CHW + j*64
  const int st_dst = ((cq >> 1) * 16 + px) * 8 + (cq & 1) * 4;
  const int boff   = g * 128 + m * 8;

  // ---- prologue: s0 -> sbuf[0], z1 -> zbuf[1], z2 -> zbuf[2]; issue z3 ----
  {
    u16x4 u0, u1, u2;
    #pragma unroll
    for (int j = 0; j < 4; ++j){
      u0[j] = f2bf(st_src[j * 64]);
      u1[j] = f2bf(st_src[CHW + j * 64]);
      u2[j] = f2bf(st_src[2 * CHW + j * 64]);
    }
    *(u16x4*)(&sbuf[0][st_dst]) = u0;
    *(u16x4*)(&zbuf[1][st_dst]) = u1;
    *(u16x4*)(&zbuf[2][st_dst]) = u2;
  }
  float pf[4];
  const float* pfp = st_src + 3 * (size_t)CHW;   // z3
  #pragma unroll
  for (int j = 0; j < 4; ++j) pf[j] = pfp[j * 64];
  pfp += CHW;                                    // next issue: z4
  __syncthreads();

  // k_1 from z_1 (G-waves only)
  if (role == 1){
    f32x4 glA[2] = {bsel[0], bsel[1]};
    f32x4 glB[2] = {{0,0,0,0},{0,0,0,0}};
    #pragma unroll
    for (int kc = 0; kc < 4; ++kc){
      u16x8 zfa = *(const u16x8*)(&zbuf[1][kc * 512 + boff]);
      u16x8 zfb = *(const u16x8*)(&zbuf[1][(kc + 4) * 512 + boff]);
      glA[0] = mfma_bf16(wf[0][kc],     zfa, glA[0]);
      glA[1] = mfma_bf16(wf[1][kc],     zfa, glA[1]);
      glB[0] = mfma_bf16(wf[0][kc + 4], zfb, glB[0]);
      glB[1] = mfma_bf16(wf[1][kc + 4], zfb, glB[1]);
    }
    #pragma unroll
    for (int mi = 0; mi < 2; ++mi){
      const int ro = (rw * 2 + mi) * 16 + g * 4;
      const int el = ((ro >> 3) * 16 + m) * 8 + (ro & 7);
      u16x4 kk;
      #pragma unroll
      for (int r = 0; r < 4; ++r) kk[r] = f2h(fast_sigmoid(glA[mi][r] + glB[mi][r]));
      *(u16x4*)(&kbuf[1][el]) = kk;
    }
  }
  __syncthreads();

  for (int l = 1; l < 63; ++l){
    if (role == 0){
      // ================= P: compute head, staging tail =================
      const unsigned short* sb  = sbuf[(l - 1) & 1];
      const unsigned short* zbl = zbuf[l & 3];
      const unsigned short* kb  = kbuf[l & 1];
      unsigned short* sbw = sbuf[l & 1];

      u16x4 zi4[2], k4[2];
      #pragma unroll
      for (int mi = 0; mi < 2; ++mi){
        const int ro = (rw * 2 + mi) * 16 + g * 4;
        const int el = ((ro >> 3) * 16 + m) * 8 + (ro & 7);
        zi4[mi] = *(const u16x4*)(zbl + el);
        k4[mi]  = *(const u16x4*)(kb + el);
      }

      f32x4 zpA[2] = {bsel[0], bsel[1]};
      f32x4 zpB[2] = {{0,0,0,0},{0,0,0,0}};
      __builtin_amdgcn_s_setprio(1);
      #pragma unroll
      for (int kc = 0; kc < 4; ++kc){
        u16x8 sfa = *(const u16x8*)(sb + kc * 512 + boff);
        u16x8 sfb = *(const u16x8*)(sb + (kc + 4) * 512 + boff);
        zpA[0] = mfma_bf16(wf[0][kc],     sfa, zpA[0]);
        zpA[1] = mfma_bf16(wf[1][kc],     sfa, zpA[1]);
        zpB[0] = mfma_bf16(wf[0][kc + 4], sfb, zpB[0]);
        zpB[1] = mfma_bf16(wf[1][kc + 4], sfb, zpB[1]);
      }
      __builtin_amdgcn_s_setprio(0);

      #pragma unroll
      for (int mi = 0; mi < 2; ++mi){
        const int ro = (rw * 2 + mi) * 16 + g * 4;
        const int el = ((ro >> 3) * 16 + m) * 8 + (ro & 7);
        u16x4 sh;
        #pragma unroll
        for (int r = 0; r < 4; ++r){
          float zpr = zpA[mi][r] + zpB[mi][r];
          float zh  = zpr + h2f(k4[mi][r]) * (bf2f(zi4[mi][r]) - zpr);
          sh[r] = f2bf(zh);
        }
        *(u16x4*)(sbw + el) = sh;
      }

      // staging tail: commit z_{l+2}, issue z_{l+3}
      if (l <= 61){
        u16x4 u;
        #pragma unroll
        for (int j = 0; j < 4; ++j) u[j] = f2bf(pf[j]);
        *(u16x4*)(&zbuf[(l + 2) & 3][st_dst]) = u;
      }
      if (l <= 60){
        #pragma unroll
        for (int j = 0; j < 4; ++j) pf[j] = pfp[j * 64];
        pfp += CHW;
      }
    } else {
      // ================= G: staging head, compute tail =================
      if (l <= 61){
        u16x4 u;
        #pragma unroll
        for (int j = 0; j < 4; ++j) u[j] = f2bf(pf[j]);
        *(u16x4*)(&zbuf[(l + 2) & 3][st_dst]) = u;
      }
      if (l <= 60){
        #pragma unroll
        for (int j = 0; j < 4; ++j) pf[j] = pfp[j * 64];
        pfp += CHW;
      }

      const unsigned short* zb = zbuf[(l + 1) & 3];
      unsigned short* kw = kbuf[(l + 1) & 1];

      f32x4 glA[2] = {bsel[0], bsel[1]};
      f32x4 glB[2] = {{0,0,0,0},{0,0,0,0}};
      #pragma unroll
      for (int kc = 0; kc < 4; ++kc){
        u16x8 zfa = *(const u16x8*)(zb + kc * 512 + boff);
        u16x8 zfb = *(const u16x8*)(zb + (kc + 4) * 512 + boff);
        glA[0] = mfma_bf16(wf[0][kc],     zfa, glA[0]);
        glA[1] = mfma_bf16(wf[1][kc],     zfa, glA[1]);
        glB[0] = mfma_bf16(wf[0][kc + 4], zfb, glB[0]);
        glB[1] = mfma_bf16(wf[1][kc + 4], zfb, glB[1]);
      }

      #pragma unroll
      for (int mi = 0; mi < 2; ++mi){
        const int ro = (rw * 2 + mi) * 16 + g * 4;
        const int el = ((ro >> 3) * 16 + m) * 8 + (ro & 7);
        u16x4 kk;
        #pragma unroll
        for (int r = 0; r < 4; ++r) kk[r] = f2h(fast_sigmoid(glA[mi][r] + glB[mi][r]));
        *(u16x4*)(kw + el) = kk;
      }
    }

    BAR_LDS();
  }

  // ---- peeled final step l = 63 (P only): out (f32) from regs ----
  if (role == 0){
    const unsigned short* sb  = sbuf[0];          // s_62  ((63-1)&1)
    const unsigned short* zbl = zbuf[3];          // z_63  (63&3, committed l=61)
    const unsigned short* kb  = kbuf[1];          // k_63  (63&1, written l=62)

    u16x4 zi4[2], k4[2];
    #pragma unroll
    for (int mi = 0; mi < 2; ++mi){
      const int ro = (rw * 2 + mi) * 16 + g * 4;
      const int el = ((ro >> 3) * 16 + m) * 8 + (ro & 7);
      zi4[mi] = *(const u16x4*)(zbl + el);
      k4[mi]  = *(const u16x4*)(kb + el);
    }

    f32x4 zpA[2] = {bsel[0], bsel[1]};
    f32x4 zpB[2] = {{0,0,0,0},{0,0,0,0}};
    #pragma unroll
    for (int kc = 0; kc < 4; ++kc){
      u16x8 sfa = *(const u16x8*)(sb + kc * 512 + boff);
      u16x8 sfb = *(const u16x8*)(sb + (kc + 4) * 512 + boff);
      zpA[0] = mfma_bf16(wf[0][kc],     sfa, zpA[0]);
      zpA[1] = mfma_bf16(wf[1][kc],     sfa, zpA[1]);
      zpB[0] = mfma_bf16(wf[0][kc + 4], sfb, zpB[0]);
      zpB[1] = mfma_bf16(wf[1][kc + 4], sfb, zpB[1]);
    }

    #pragma unroll
    for (int mi = 0; mi < 2; ++mi){
      const int ro = (rw * 2 + mi) * 16 + g * 4;
      float* o = out + ((size_t)b * 256 + ro) * 64 + q * 16 + m;
      #pragma unroll
      for (int r = 0; r < 4; ++r){
        float zpr = zpA[mi][r] + zpB[mi][r];
        o[r * 64] = zpr + h2f(k4[mi][r]) * (bf2f(zi4[mi][r]) - zpr);
      }
    }
  }
}

extern "C" void kernel_launch(void* const* d_in, const int* in_sizes, int n_in,
                              void* d_out, int out_size, void* d_ws, size_t ws_size,
                              hipStream_t stream)
{
  const float* z  = (const float*)d_in[0];
  const float* Wg = (const float*)d_in[1];
  const float* bg = (const float*)d_in[2];
  const float* Wp = (const float*)d_in[3];
  const float* bp = (const float*)d_in[4];
  float* out = (float*)d_out;
  hipLaunchKernelGGL(kalman_kernel, dim3(256), dim3(1024), 0, stream,
                     z, Wg, bg, Wp, bp, out);
}